// Round 10
// baseline (161.300 us; speedup 1.0000x reference)
//
#include <hip/hip_runtime.h>
#include <hip/hip_bf16.h>
#include <stdint.h>

typedef short s16x8 __attribute__((ext_vector_type(8)));
typedef float f32x4 __attribute__((ext_vector_type(4)));

#define BSZ 2
#define SQL 2048
#define DMODEL 1024
#define NHEAD 16
#define DKH 64

#if __has_builtin(__builtin_amdgcn_exp2f)
#define EXP2(x) __builtin_amdgcn_exp2f(x)
#else
#define EXP2(x) exp2f(x)
#endif

// fp32 -> bf16 round-to-nearest-even
__device__ __forceinline__ ushort f2bf(float f) {
  uint32_t u = __float_as_uint(f);
  u += 0x7fffu + ((u >> 16) & 1u);
  return (ushort)(u >> 16);
}

// pack two f32 -> 2x bf16 in one u32 (lo -> low half), RNE
__device__ __forceinline__ uint32_t cvtpk_bf16(float lo, float hi) {
  uint32_t r;
  asm("v_cvt_pk_bf16_f32 %0, %1, %2" : "=v"(r) : "v"(lo), "v"(hi));
  return r;
}

// max-reduce across the 16-lane DPP row via row_ror 1,2,4,8 (VALU, no DS pipe)
__device__ __forceinline__ float rowmax16(float x) {
  x = fmaxf(x, __int_as_float(__builtin_amdgcn_update_dpp(0, __float_as_int(x), 0x121, 0xf, 0xf, true)));
  x = fmaxf(x, __int_as_float(__builtin_amdgcn_update_dpp(0, __float_as_int(x), 0x122, 0xf, 0xf, true)));
  x = fmaxf(x, __int_as_float(__builtin_amdgcn_update_dpp(0, __float_as_int(x), 0x124, 0xf, 0xf, true)));
  x = fmaxf(x, __int_as_float(__builtin_amdgcn_update_dpp(0, __float_as_int(x), 0x128, 0xf, 0xf, true)));
  return x;
}

// async global->LDS, 16B per lane. LDS dest must be wave-uniform base; HW adds lane*16.
__device__ __forceinline__ void gload_lds16(const ushort* g, ushort* l) {
  __builtin_amdgcn_global_load_lds((const __attribute__((address_space(1))) void*)g,
                                   (__attribute__((address_space(3))) void*)l,
                                   16, 0, 0);
}

// ---------------- fp32 -> bf16 conversion (single launch, q/k/v + 4 weights) ----------------
__global__ void cvt_all(const float* __restrict__ q, const float* __restrict__ k,
                        const float* __restrict__ v, const float* __restrict__ wq,
                        const float* __restrict__ wk, const float* __restrict__ wv,
                        const float* __restrict__ wo, ushort* __restrict__ dq,
                        ushort* __restrict__ dk, ushort* __restrict__ dv,
                        ushort* __restrict__ dwq, ushort* __restrict__ dwk,
                        ushort* __restrict__ dwv, ushort* __restrict__ dwo) {
  int b = blockIdx.x;
  const float* s; ushort* d; int off;
  if (b < 4096)       { s = q;  d = dq;  off = b; }
  else if (b < 8192)  { s = k;  d = dk;  off = b - 4096; }
  else if (b < 12288) { s = v;  d = dv;  off = b - 8192; }
  else if (b < 13312) { s = wq; d = dwq; off = b - 12288; }
  else if (b < 14336) { s = wk; d = dwk; off = b - 13312; }
  else if (b < 15360) { s = wv; d = dwv; off = b - 14336; }
  else                { s = wo; d = dwo; off = b - 15360; }
  int i = (off * 256 + threadIdx.x) * 4;
  float4 x = *(const float4*)(s + i);
  ushort4 o;
  o.x = f2bf(x.x); o.y = f2bf(x.y); o.z = f2bf(x.z); o.w = f2bf(x.w);
  *(ushort4*)(d + i) = o;
}

// ---------------- GEMM core 128x128, chunk-major LDS (conflict-free b128 reads) ------
// LDS holds 16B chunks at pos = c*128 + r (c = k-chunk 0..3, r = row 0..127).
// Staged by permuting the GLOBAL source (LDS dest stays linear for gload_lds16).
// Fragment read for (row R, chunk g): elems g*1024 + R*8 -> 16 lanes = 256B contig.
__device__ __forceinline__ void gemm_core(const ushort* __restrict__ A,
                                          const ushort* __restrict__ B,
                                          ushort* sA, ushort* sB, f32x4 (&acc)[4][4]) {
  const int t = threadIdx.x, w = t >> 6, lane = t & 63;
  const int lrow = lane & 15, g = lane >> 4;
  const int m0 = blockIdx.x * 128, n0 = blockIdx.y * 128;
  const int wm = (w >> 1) * 64, wn = (w & 1) * 64;

  auto stage = [&](int kt, int buf) {
#pragma unroll
    for (int i = 0; i < 2; ++i) {
      int ci = i * 256 + t;
      int r = ci & 127, c = ci >> 7;     // chunk-major: pos ci holds (row r, chunk c)
      gload_lds16(A + (size_t)(m0 + r) * 1024 + kt * 32 + c * 8,
                  sA + buf * 4096 + (i * 256 + w * 64) * 8);
      gload_lds16(B + (size_t)(n0 + r) * 1024 + kt * 32 + c * 8,
                  sB + buf * 4096 + (i * 256 + w * 64) * 8);
    }
  };

  stage(0, 0);
  for (int kt = 0; kt < 32; ++kt) {
    const int cur = kt & 1;
    if (kt < 31) {
      stage(kt + 1, cur ^ 1);
      asm volatile("s_waitcnt vmcnt(4)" ::: "memory");
    } else {
      asm volatile("s_waitcnt vmcnt(0)" ::: "memory");
    }
    __builtin_amdgcn_s_barrier();
    __builtin_amdgcn_sched_barrier(0);
    const ushort* pA = sA + cur * 4096;
    const ushort* pB = sB + cur * 4096;
    s16x8 af[4], bfr[4];
#pragma unroll
    for (int mi = 0; mi < 4; ++mi)
      af[mi] = *(const s16x8*)(pA + g * 1024 + (wm + mi * 16 + lrow) * 8);
#pragma unroll
    for (int ni = 0; ni < 4; ++ni)
      bfr[ni] = *(const s16x8*)(pB + g * 1024 + (wn + ni * 16 + lrow) * 8);
    __builtin_amdgcn_s_setprio(1);
#pragma unroll
    for (int mi = 0; mi < 4; ++mi)
#pragma unroll
      for (int ni = 0; ni < 4; ++ni)
        acc[mi][ni] = __builtin_amdgcn_mfma_f32_16x16x32_bf16(af[mi], bfr[ni], acc[mi][ni], 0, 0, 0);
    __builtin_amdgcn_s_setprio(0);
    asm volatile("s_waitcnt lgkmcnt(0)" ::: "memory");
    __builtin_amdgcn_s_barrier();
  }
}

// epilogue for bf16 head-major / permuted-transposed-V outputs (r4-verified)
__device__ __forceinline__ void epi_heads(f32x4 (&acc)[4][4], ushort* D, float scale, bool vtrans) {
  const int lane = threadIdx.x & 63, w = threadIdx.x >> 6;
  const int m0 = blockIdx.x * 128, n0 = blockIdx.y * 128;
  const int wm = (w >> 1) * 64, wn = (w & 1) * 64;
#pragma unroll
  for (int mi = 0; mi < 4; ++mi)
#pragma unroll
    for (int ni = 0; ni < 4; ++ni)
#pragma unroll
      for (int r = 0; r < 4; ++r) {
        int m = m0 + wm + mi * 16 + (lane >> 4) * 4 + r;
        int n = n0 + wn + ni * 16 + (lane & 15);
        ushort bv = f2bf(acc[mi][ni][r] * scale);
        int b = m >> 11, s = m & 2047, h = n >> 6, d = n & 63;
        if (vtrans) {
          // k-permutation inside each 64-tile: idx(k) = (k&15)*4 + (k>>4)
          int sp = (s & ~63) | (((s & 15) << 2) | ((s >> 4) & 3));
          D[((size_t)((b * 16 + h) * 64 + d)) * 2048 + sp] = bv;   // V^T permuted
        } else {
          D[((size_t)((b * 16 + h) * 2048 + s)) * 64 + d] = bv;    // Qh/Kh [bh][s][d]
        }
      }
}

__global__ __launch_bounds__(256) void gemm_qkv(const ushort* __restrict__ qb,
                                                const ushort* __restrict__ kb,
                                                const ushort* __restrict__ vb,
                                                const ushort* __restrict__ wqb,
                                                const ushort* __restrict__ wkb,
                                                const ushort* __restrict__ wvb,
                                                ushort* __restrict__ Qh,
                                                ushort* __restrict__ Kh,
                                                ushort* __restrict__ Vt) {
  __shared__ __align__(16) ushort sA[2 * 4096];
  __shared__ __align__(16) ushort sB[2 * 4096];
  const int z = blockIdx.z;
  const ushort* A = (z == 0) ? qb : (z == 1) ? kb : vb;
  const ushort* B = (z == 0) ? wqb : (z == 1) ? wkb : wvb;
  f32x4 acc[4][4] = {};
  gemm_core(A, B, sA, sB, acc);
  ushort* D = (z == 0) ? Qh : (z == 1) ? Kh : Vt;
  // Q pre-scaled by 1/sqrt(dk) * log2(e) so softmax runs in exp2 domain
  epi_heads(acc, D, (z == 0) ? 0.18033688f : 1.0f, z == 2);
}

// ---------------- gemm_out: 64x128 tiles, chunk-major LDS, Z x Wo^T -> fp32 ----------------
__global__ __launch_bounds__(256) void gemm_out64(const ushort* __restrict__ A,
                                                  const ushort* __restrict__ B,
                                                  float* __restrict__ D) {
  __shared__ __align__(16) ushort sA[2 * 2048];
  __shared__ __align__(16) ushort sB[2 * 4096];
  const int t = threadIdx.x, w = t >> 6, lane = t & 63;
  const int lrow = lane & 15, g = lane >> 4;
  const int m0 = blockIdx.x * 64, n0 = blockIdx.y * 128;
  const int wm = (w >> 1) * 32, wn = (w & 1) * 64;
  f32x4 acc[2][4] = {};

  auto stage = [&](int kt, int buf) {
    {
      int r = t & 63, c = t >> 6;        // A: 256 chunks, plane = 64 rows
      gload_lds16(A + (size_t)(m0 + r) * 1024 + kt * 32 + c * 8,
                  sA + buf * 2048 + (w * 64) * 8);
    }
#pragma unroll
    for (int i = 0; i < 2; ++i) {
      int ci = i * 256 + t;
      int r = ci & 127, c = ci >> 7;     // B: 512 chunks, plane = 128 rows
      gload_lds16(B + (size_t)(n0 + r) * 1024 + kt * 32 + c * 8,
                  sB + buf * 4096 + (i * 256 + w * 64) * 8);
    }
  };

  stage(0, 0);
  for (int kt = 0; kt < 32; ++kt) {
    const int cur = kt & 1;
    if (kt < 31) {
      stage(kt + 1, cur ^ 1);
      asm volatile("s_waitcnt vmcnt(3)" ::: "memory");
    } else {
      asm volatile("s_waitcnt vmcnt(0)" ::: "memory");
    }
    __builtin_amdgcn_s_barrier();
    __builtin_amdgcn_sched_barrier(0);
    const ushort* pA = sA + cur * 2048;
    const ushort* pB = sB + cur * 4096;
    s16x8 af[2], bfr[4];
#pragma unroll
    for (int mi = 0; mi < 2; ++mi)
      af[mi] = *(const s16x8*)(pA + g * 512 + (wm + mi * 16 + lrow) * 8);
#pragma unroll
    for (int ni = 0; ni < 4; ++ni)
      bfr[ni] = *(const s16x8*)(pB + g * 1024 + (wn + ni * 16 + lrow) * 8);
    __builtin_amdgcn_s_setprio(1);
#pragma unroll
    for (int mi = 0; mi < 2; ++mi)
#pragma unroll
      for (int ni = 0; ni < 4; ++ni)
        acc[mi][ni] = __builtin_amdgcn_mfma_f32_16x16x32_bf16(af[mi], bfr[ni], acc[mi][ni], 0, 0, 0);
    __builtin_amdgcn_s_setprio(0);
    asm volatile("s_waitcnt lgkmcnt(0)" ::: "memory");
    __builtin_amdgcn_s_barrier();
  }

#pragma unroll
  for (int mi = 0; mi < 2; ++mi)
#pragma unroll
    for (int ni = 0; ni < 4; ++ni)
#pragma unroll
      for (int r = 0; r < 4; ++r) {
        int m = m0 + wm + mi * 16 + (lane >> 4) * 4 + r;
        int n = n0 + wn + ni * 16 + (lane & 15);
        D[(size_t)m * 1024 + n] = acc[mi][ni][r];
      }
}

// ---------------- causal flash attention (r9 kernel, unchanged) ----------------
// grid (16, B*H), 512 threads. Waves 0-3 own q-tile p, waves 4-7 own 31-p.
// Each wave: 16 q-rows. KV tiles of 64, double-buffered, counted vmcnt(2).
// P stored k-permuted (idx = 4*(k&15) + (k>>4)) via one b64/row-quad; Vt global
// is pre-permuted to match, so PV dot products are k-permutation invariant.
__global__ __launch_bounds__(512) void attn_fwd(const ushort* __restrict__ Qh,
                                                const ushort* __restrict__ Kh,
                                                const ushort* __restrict__ Vt,
                                                ushort* __restrict__ Z) {
  __shared__ __align__(16) ushort sK[2][64 * 64];   // [k][d], chunk-XOR swizzled
  __shared__ __align__(16) ushort sV[2][64 * 64];   // [d][pos], chunk-XOR swizzled
  __shared__ __align__(16) ushort sP[8][16 * 72];   // per-wave P (k-permuted cols)
  const int t = threadIdx.x, w = t >> 6, lane = t & 63;
  const int lcol = lane & 15, lhi = lane >> 4;
  const int p = blockIdx.x, bh = blockIdx.y;
  const int qlo = p, qhi = 31 - p;
  const int setid = w >> 2;
  const int qtile = setid ? qhi : qlo;
  const int qr0 = qtile * 64 + (w & 3) * 16;
  const ushort* Qb = Qh + (size_t)bh * SQL * DKH;
  const ushort* Kb = Kh + (size_t)bh * SQL * DKH;
  const ushort* Vb = Vt + (size_t)bh * DKH * SQL;

  s16x8 qf0, qf1;
  {
    const ushort* qp = Qb + (size_t)(qr0 + lcol) * DKH + lhi * 8;
    qf0 = *(const s16x8*)qp;
    qf1 = *(const s16x8*)(qp + 32);
  }
  float mr[4], lrp[4];
  f32x4 o[4] = {};
#pragma unroll
  for (int r = 0; r < 4; ++r) { mr[r] = -1e30f; lrp[r] = 0.f; }
  ushort* Pw = &sP[w][0];

  auto stage = [&](int kb, int buf) {
    int row = t >> 3, cc = t & 7;
    int scz = cc ^ (row & 7);        // pre-swizzled source -> linear LDS dest
    gload_lds16(Kb + (size_t)(kb * 64 + row) * DKH + scz * 8, &sK[buf][w * 512]);
    gload_lds16(Vb + (size_t)row * SQL + kb * 64 + scz * 8, &sV[buf][w * 512]);
  };

  const int nkb = qhi + 1;
  stage(0, 0);
  for (int kb = 0; kb < nkb; ++kb) {
    const int cur = kb & 1;
    if (kb + 1 < nkb) {
      stage(kb + 1, cur ^ 1);                        // 2 vmem in flight
      asm volatile("s_waitcnt vmcnt(2)" ::: "memory");
    } else {
      asm volatile("s_waitcnt vmcnt(0)" ::: "memory");
    }
    __builtin_amdgcn_s_barrier();
    __builtin_amdgcn_sched_barrier(0);
    const bool act = setid || (kb <= qlo);
    if (act) {
      const ushort* pK = &sK[cur][0];
      const ushort* pV = &sV[cur][0];
      // QK^T
      f32x4 sc4[4];
      __builtin_amdgcn_s_setprio(1);
#pragma unroll
      for (int ktt = 0; ktt < 4; ++ktt) {
        int row = ktt * 16 + lcol;
        int c0 = lhi ^ (row & 7);
        int c1 = (lhi + 4) ^ (row & 7);
        s16x8 k0 = *(const s16x8*)(pK + row * 64 + c0 * 8);
        s16x8 k1 = *(const s16x8*)(pK + row * 64 + c1 * 8);
        f32x4 a = {};
        a = __builtin_amdgcn_mfma_f32_16x16x32_bf16(qf0, k0, a, 0, 0, 0);
        a = __builtin_amdgcn_mfma_f32_16x16x32_bf16(qf1, k1, a, 0, 0, 0);
        sc4[ktt] = a;
      }
      __builtin_amdgcn_s_setprio(0);
      // causal mask on the diagonal tile
      if (kb == qtile) {
#pragma unroll
        for (int ktt = 0; ktt < 4; ++ktt) {
          int kloc = ktt * 16 + lcol;
#pragma unroll
          for (int r = 0; r < 4; ++r)
            if (kloc > (w & 3) * 16 + lhi * 4 + r) sc4[ktt][r] = -1e30f;
        }
      }
      // online softmax (log2 domain), defer-max rescale
      float tm4[4];
#pragma unroll
      for (int r = 0; r < 4; ++r) {
        float tm = fmaxf(fmaxf(sc4[0][r], sc4[1][r]), fmaxf(sc4[2][r], sc4[3][r]));
        tm4[r] = rowmax16(tm);
      }
      bool grow = (tm4[0] > mr[0] + 8.f) || (tm4[1] > mr[1] + 8.f) ||
                  (tm4[2] > mr[2] + 8.f) || (tm4[3] > mr[3] + 8.f);
      if (__any((int)grow)) {
#pragma unroll
        for (int r = 0; r < 4; ++r) {
          float mn = fmaxf(mr[r], tm4[r]);
          float al = EXP2(mr[r] - mn);
          lrp[r] *= al;
          o[0][r] *= al; o[1][r] *= al; o[2][r] *= al; o[3][r] *= al;
          mr[r] = mn;
        }
      }
#pragma unroll
      for (int r = 0; r < 4; ++r) {
        float p0 = EXP2(sc4[0][r] - mr[r]);
        float p1 = EXP2(sc4[1][r] - mr[r]);
        float p2 = EXP2(sc4[2][r] - mr[r]);
        float p3 = EXP2(sc4[3][r] - mr[r]);
        lrp[r] += (p0 + p1) + (p2 + p3);
        uint2 pk;
        pk.x = cvtpk_bf16(p0, p1);
        pk.y = cvtpk_bf16(p2, p3);
        // permuted store: (k=ktt*16+lcol) -> idx 4*lcol+ktt; one b64 covers ktt 0..3
        *(uint2*)(Pw + (lhi * 4 + r) * 72 + lcol * 4) = pk;
      }
      // PV (Vt global pre-permuted to match the P permutation)
      __builtin_amdgcn_s_setprio(1);
#pragma unroll
      for (int kc = 0; kc < 2; ++kc) {
        s16x8 pf = *(const s16x8*)(Pw + lcol * 72 + kc * 32 + lhi * 8);
#pragma unroll
        for (int dt = 0; dt < 4; ++dt) {
          int row = dt * 16 + lcol;
          int cc = (lhi + 4 * kc) ^ (row & 7);
          s16x8 vf = *(const s16x8*)(pV + row * 64 + cc * 8);
          o[dt] = __builtin_amdgcn_mfma_f32_16x16x32_bf16(pf, vf, o[dt], 0, 0, 0);
        }
      }
      __builtin_amdgcn_s_setprio(0);
    }
    asm volatile("s_waitcnt lgkmcnt(0)" ::: "memory");
    __builtin_amdgcn_s_barrier();
  }

  // epilogue: reduce denominators over the 16 k-lanes, normalize, write Z
  const int b = bh >> 4, h = bh & 15;
#pragma unroll
  for (int r = 0; r < 4; ++r) {
    float sum = lrp[r];
    sum += __shfl_xor(sum, 1);
    sum += __shfl_xor(sum, 2);
    sum += __shfl_xor(sum, 4);
    sum += __shfl_xor(sum, 8);
    float inv = 1.0f / sum;
    int q = qr0 + lhi * 4 + r;
    size_t base = ((size_t)(b * SQL + q)) * DMODEL + h * DKH + lcol;
#pragma unroll
    for (int dt = 0; dt < 4; ++dt)
      Z[base + dt * 16] = f2bf(o[dt][r] * inv);
  }
}

// ---------------- launch ----------------
extern "C" void kernel_launch(void* const* d_in, const int* in_sizes, int n_in,
                              void* d_out, int out_size, void* d_ws, size_t ws_size,
                              hipStream_t stream) {
  const float* q = (const float*)d_in[0];
  const float* k = (const float*)d_in[1];
  const float* v = (const float*)d_in[2];
  // d_in[3] = causal mask (bool) -- derived analytically, ignored
  const float* wq = (const float*)d_in[4];
  const float* wk = (const float*)d_in[5];
  const float* wv = (const float*)d_in[6];
  const float* wo = (const float*)d_in[7];

  const size_t NBIG = (size_t)BSZ * SQL * DMODEL;   // 4194304
  const size_t NW = (size_t)DMODEL * DMODEL;        // 1048576
  ushort* qb = (ushort*)d_ws;
  ushort* kb = qb + NBIG;
  ushort* vb = kb + NBIG;
  ushort* wqb = vb + NBIG;
  ushort* wkb = wqb + NW;
  ushort* wvb = wkb + NW;
  ushort* wob = wvb + NW;
  ushort* Qh = wob + NW;
  ushort* Kh = Qh + NBIG;
  ushort* Vt = Kh + NBIG;
  ushort* Z  = Vt + NBIG;   // total 64 MiB of d_ws

  cvt_all<<<dim3(16384), 256, 0, stream>>>(q, k, v, wq, wk, wv, wo,
                                           qb, kb, vb, wqb, wkb, wvb, wob);
  gemm_qkv<<<dim3(32, 8, 3), 256, 0, stream>>>(qb, kb, vb, wqb, wkb, wvb, Qh, Kh, Vt);
  attn_fwd<<<dim3(16, BSZ * NHEAD), 512, 0, stream>>>(Qh, Kh, Vt, Z);
  gemm_out64<<<dim3(64, 8), 256, 0, stream>>>(Z, wob, (float*)d_out);
}

// Round 11
// 129.780 us; speedup vs baseline: 1.2429x; 1.2429x over previous
//
#include <hip/hip_runtime.h>
#include <hip/hip_bf16.h>
#include <stdint.h>

typedef short s16x8 __attribute__((ext_vector_type(8)));
typedef float f32x4 __attribute__((ext_vector_type(4)));

#define BSZ 2
#define SQL 2048
#define DMODEL 1024
#define NHEAD 16
#define DKH 64

#if __has_builtin(__builtin_amdgcn_exp2f)
#define EXP2(x) __builtin_amdgcn_exp2f(x)
#else
#define EXP2(x) exp2f(x)
#endif

// fp32 -> bf16 round-to-nearest-even
__device__ __forceinline__ ushort f2bf(float f) {
  uint32_t u = __float_as_uint(f);
  u += 0x7fffu + ((u >> 16) & 1u);
  return (ushort)(u >> 16);
}

// pack two f32 -> 2x bf16 in one u32 (lo -> low half), RNE
__device__ __forceinline__ uint32_t cvtpk_bf16(float lo, float hi) {
  uint32_t r;
  asm("v_cvt_pk_bf16_f32 %0, %1, %2" : "=v"(r) : "v"(lo), "v"(hi));
  return r;
}

// max-reduce across the 16-lane DPP row via row_ror 1,2,4,8 (VALU, no DS pipe)
__device__ __forceinline__ float rowmax16(float x) {
  x = fmaxf(x, __int_as_float(__builtin_amdgcn_update_dpp(0, __float_as_int(x), 0x121, 0xf, 0xf, true)));
  x = fmaxf(x, __int_as_float(__builtin_amdgcn_update_dpp(0, __float_as_int(x), 0x122, 0xf, 0xf, true)));
  x = fmaxf(x, __int_as_float(__builtin_amdgcn_update_dpp(0, __float_as_int(x), 0x124, 0xf, 0xf, true)));
  x = fmaxf(x, __int_as_float(__builtin_amdgcn_update_dpp(0, __float_as_int(x), 0x128, 0xf, 0xf, true)));
  return x;
}

// async global->LDS, 16B per lane. LDS dest must be wave-uniform base; HW adds lane*16.
__device__ __forceinline__ void gload_lds16(const ushort* g, ushort* l) {
  __builtin_amdgcn_global_load_lds((const __attribute__((address_space(1))) void*)g,
                                   (__attribute__((address_space(3))) void*)l,
                                   16, 0, 0);
}

// ---------------- fp32 -> bf16 conversion (single launch, q/k/v + 4 weights) ----------------
__global__ void cvt_all(const float* __restrict__ q, const float* __restrict__ k,
                        const float* __restrict__ v, const float* __restrict__ wq,
                        const float* __restrict__ wk, const float* __restrict__ wv,
                        const float* __restrict__ wo, ushort* __restrict__ dq,
                        ushort* __restrict__ dk, ushort* __restrict__ dv,
                        ushort* __restrict__ dwq, ushort* __restrict__ dwk,
                        ushort* __restrict__ dwv, ushort* __restrict__ dwo) {
  int b = blockIdx.x;
  const float* s; ushort* d; int off;
  if (b < 4096)       { s = q;  d = dq;  off = b; }
  else if (b < 8192)  { s = k;  d = dk;  off = b - 4096; }
  else if (b < 12288) { s = v;  d = dv;  off = b - 8192; }
  else if (b < 13312) { s = wq; d = dwq; off = b - 12288; }
  else if (b < 14336) { s = wk; d = dwk; off = b - 13312; }
  else if (b < 15360) { s = wv; d = dwv; off = b - 14336; }
  else                { s = wo; d = dwo; off = b - 15360; }
  int i = (off * 256 + threadIdx.x) * 4;
  float4 x = *(const float4*)(s + i);
  ushort4 o;
  o.x = f2bf(x.x); o.y = f2bf(x.y); o.z = f2bf(x.z); o.w = f2bf(x.w);
  *(ushort4*)(d + i) = o;
}

// ---------------- GEMM core 128x128: C = A[M,K] * B[N,K]^T ----------------
// Row-major LDS (coalesced staging, as r3) + within-row chunk swizzle
// c' = c ^ ((row>>1)&3): staging stays coalesced (permutes inside each 64B
// row window); fragment reads spread all 32 banks exactly 2x (free, m136).
__device__ __forceinline__ void gemm_core(const ushort* __restrict__ A,
                                          const ushort* __restrict__ B,
                                          ushort* sA, ushort* sB, f32x4 (&acc)[4][4]) {
  const int t = threadIdx.x, w = t >> 6, lane = t & 63;
  const int lrow = lane & 15, g = lane >> 4;
  const int swz = (lrow >> 1) & 3;            // per-lane chunk swizzle for reads
  const int m0 = blockIdx.x * 128, n0 = blockIdx.y * 128;
  const int wm = (w >> 1) * 64, wn = (w & 1) * 64;

  auto stage = [&](int kt, int buf) {
#pragma unroll
    for (int i = 0; i < 2; ++i) {
      int ci = i * 256 + t;
      int row = ci >> 2;                       // 4 chunks per 64B row
      int cs = (ci & 3) ^ ((row >> 1) & 3);    // within-row swizzled chunk
      gload_lds16(A + (size_t)(m0 + row) * 1024 + kt * 32 + cs * 8,
                  sA + buf * 4096 + (i * 256 + w * 64) * 8);
      gload_lds16(B + (size_t)(n0 + row) * 1024 + kt * 32 + cs * 8,
                  sB + buf * 4096 + (i * 256 + w * 64) * 8);
    }
  };

  stage(0, 0);
  for (int kt = 0; kt < 32; ++kt) {
    const int cur = kt & 1;
    if (kt < 31) {
      stage(kt + 1, cur ^ 1);
      asm volatile("s_waitcnt vmcnt(4)" ::: "memory");
    } else {
      asm volatile("s_waitcnt vmcnt(0)" ::: "memory");
    }
    __builtin_amdgcn_s_barrier();
    __builtin_amdgcn_sched_barrier(0);
    const ushort* pA = sA + cur * 4096;
    const ushort* pB = sB + cur * 4096;
    const int gs = (g ^ swz) * 8;
    s16x8 af[4], bfr[4];
#pragma unroll
    for (int mi = 0; mi < 4; ++mi)
      af[mi] = *(const s16x8*)(pA + (wm + mi * 16 + lrow) * 32 + gs);
#pragma unroll
    for (int ni = 0; ni < 4; ++ni)
      bfr[ni] = *(const s16x8*)(pB + (wn + ni * 16 + lrow) * 32 + gs);
    __builtin_amdgcn_s_setprio(1);
#pragma unroll
    for (int mi = 0; mi < 4; ++mi)
#pragma unroll
      for (int ni = 0; ni < 4; ++ni)
        acc[mi][ni] = __builtin_amdgcn_mfma_f32_16x16x32_bf16(af[mi], bfr[ni], acc[mi][ni], 0, 0, 0);
    __builtin_amdgcn_s_setprio(0);
    asm volatile("s_waitcnt lgkmcnt(0)" ::: "memory");
    __builtin_amdgcn_s_barrier();
  }
}

// epilogue for bf16 head-major / permuted-transposed-V outputs (r4-verified)
__device__ __forceinline__ void epi_heads(f32x4 (&acc)[4][4], ushort* D, float scale, bool vtrans) {
  const int lane = threadIdx.x & 63, w = threadIdx.x >> 6;
  const int m0 = blockIdx.x * 128, n0 = blockIdx.y * 128;
  const int wm = (w >> 1) * 64, wn = (w & 1) * 64;
#pragma unroll
  for (int mi = 0; mi < 4; ++mi)
#pragma unroll
    for (int ni = 0; ni < 4; ++ni)
#pragma unroll
      for (int r = 0; r < 4; ++r) {
        int m = m0 + wm + mi * 16 + (lane >> 4) * 4 + r;
        int n = n0 + wn + ni * 16 + (lane & 15);
        ushort bv = f2bf(acc[mi][ni][r] * scale);
        int b = m >> 11, s = m & 2047, h = n >> 6, d = n & 63;
        if (vtrans) {
          // k-permutation inside each 64-tile: idx(k) = (k&15)*4 + (k>>4)
          int sp = (s & ~63) | (((s & 15) << 2) | ((s >> 4) & 3));
          D[((size_t)((b * 16 + h) * 64 + d)) * 2048 + sp] = bv;   // V^T permuted
        } else {
          D[((size_t)((b * 16 + h) * 2048 + s)) * 64 + d] = bv;    // Qh/Kh [bh][s][d]
        }
      }
}

__global__ __launch_bounds__(256) void gemm_qkv(const ushort* __restrict__ qb,
                                                const ushort* __restrict__ kb,
                                                const ushort* __restrict__ vb,
                                                const ushort* __restrict__ wqb,
                                                const ushort* __restrict__ wkb,
                                                const ushort* __restrict__ wvb,
                                                ushort* __restrict__ Qh,
                                                ushort* __restrict__ Kh,
                                                ushort* __restrict__ Vt) {
  __shared__ __align__(16) ushort sA[2 * 4096];
  __shared__ __align__(16) ushort sB[2 * 4096];
  const int z = blockIdx.z;
  const ushort* A = (z == 0) ? qb : (z == 1) ? kb : vb;
  const ushort* B = (z == 0) ? wqb : (z == 1) ? wkb : wvb;
  f32x4 acc[4][4] = {};
  gemm_core(A, B, sA, sB, acc);
  ushort* D = (z == 0) ? Qh : (z == 1) ? Kh : Vt;
  // Q pre-scaled by 1/sqrt(dk) * log2(e) so softmax runs in exp2 domain
  epi_heads(acc, D, (z == 0) ? 0.18033688f : 1.0f, z == 2);
}

// ---------------- gemm_out: 64x128 tiles, same swizzle, Z x Wo^T -> fp32 ----------------
__global__ __launch_bounds__(256) void gemm_out64(const ushort* __restrict__ A,
                                                  const ushort* __restrict__ B,
                                                  float* __restrict__ D) {
  __shared__ __align__(16) ushort sA[2 * 2048];
  __shared__ __align__(16) ushort sB[2 * 4096];
  const int t = threadIdx.x, w = t >> 6, lane = t & 63;
  const int lrow = lane & 15, g = lane >> 4;
  const int swz = (lrow >> 1) & 3;
  const int m0 = blockIdx.x * 64, n0 = blockIdx.y * 128;
  const int wm = (w >> 1) * 32, wn = (w & 1) * 64;
  f32x4 acc[2][4] = {};

  auto stage = [&](int kt, int buf) {
    {
      int row = t >> 2;
      int cs = (t & 3) ^ ((row >> 1) & 3);
      gload_lds16(A + (size_t)(m0 + row) * 1024 + kt * 32 + cs * 8,
                  sA + buf * 2048 + (w * 64) * 8);
    }
#pragma unroll
    for (int i = 0; i < 2; ++i) {
      int ci = i * 256 + t;
      int row = ci >> 2;
      int cs = (ci & 3) ^ ((row >> 1) & 3);
      gload_lds16(B + (size_t)(n0 + row) * 1024 + kt * 32 + cs * 8,
                  sB + buf * 4096 + (i * 256 + w * 64) * 8);
    }
  };

  stage(0, 0);
  for (int kt = 0; kt < 32; ++kt) {
    const int cur = kt & 1;
    if (kt < 31) {
      stage(kt + 1, cur ^ 1);
      asm volatile("s_waitcnt vmcnt(3)" ::: "memory");
    } else {
      asm volatile("s_waitcnt vmcnt(0)" ::: "memory");
    }
    __builtin_amdgcn_s_barrier();
    __builtin_amdgcn_sched_barrier(0);
    const ushort* pA = sA + cur * 2048;
    const ushort* pB = sB + cur * 4096;
    const int gs = (g ^ swz) * 8;
    s16x8 af[2], bfr[4];
#pragma unroll
    for (int mi = 0; mi < 2; ++mi)
      af[mi] = *(const s16x8*)(pA + (wm + mi * 16 + lrow) * 32 + gs);
#pragma unroll
    for (int ni = 0; ni < 4; ++ni)
      bfr[ni] = *(const s16x8*)(pB + (wn + ni * 16 + lrow) * 32 + gs);
    __builtin_amdgcn_s_setprio(1);
#pragma unroll
    for (int mi = 0; mi < 2; ++mi)
#pragma unroll
      for (int ni = 0; ni < 4; ++ni)
        acc[mi][ni] = __builtin_amdgcn_mfma_f32_16x16x32_bf16(af[mi], bfr[ni], acc[mi][ni], 0, 0, 0);
    __builtin_amdgcn_s_setprio(0);
    asm volatile("s_waitcnt lgkmcnt(0)" ::: "memory");
    __builtin_amdgcn_s_barrier();
  }

#pragma unroll
  for (int mi = 0; mi < 2; ++mi)
#pragma unroll
    for (int ni = 0; ni < 4; ++ni)
#pragma unroll
      for (int r = 0; r < 4; ++r) {
        int m = m0 + wm + mi * 16 + (lane >> 4) * 4 + r;
        int n = n0 + wn + ni * 16 + (lane & 15);
        D[(size_t)m * 1024 + n] = acc[mi][ni][r];
      }
}

// ---------------- causal flash attention (r9 kernel, unchanged) ----------------
// grid (16, B*H), 512 threads. Waves 0-3 own q-tile p, waves 4-7 own 31-p.
// Each wave: 16 q-rows. KV tiles of 64, double-buffered, counted vmcnt(2).
// P stored k-permuted (idx = 4*(k&15) + (k>>4)) via one b64/row-quad; Vt global
// is pre-permuted to match, so PV dot products are k-permutation invariant.
__global__ __launch_bounds__(512) void attn_fwd(const ushort* __restrict__ Qh,
                                                const ushort* __restrict__ Kh,
                                                const ushort* __restrict__ Vt,
                                                ushort* __restrict__ Z) {
  __shared__ __align__(16) ushort sK[2][64 * 64];   // [k][d], chunk-XOR swizzled
  __shared__ __align__(16) ushort sV[2][64 * 64];   // [d][pos], chunk-XOR swizzled
  __shared__ __align__(16) ushort sP[8][16 * 72];   // per-wave P (k-permuted cols)
  const int t = threadIdx.x, w = t >> 6, lane = t & 63;
  const int lcol = lane & 15, lhi = lane >> 4;
  const int p = blockIdx.x, bh = blockIdx.y;
  const int qlo = p, qhi = 31 - p;
  const int setid = w >> 2;
  const int qtile = setid ? qhi : qlo;
  const int qr0 = qtile * 64 + (w & 3) * 16;
  const ushort* Qb = Qh + (size_t)bh * SQL * DKH;
  const ushort* Kb = Kh + (size_t)bh * SQL * DKH;
  const ushort* Vb = Vt + (size_t)bh * DKH * SQL;

  s16x8 qf0, qf1;
  {
    const ushort* qp = Qb + (size_t)(qr0 + lcol) * DKH + lhi * 8;
    qf0 = *(const s16x8*)qp;
    qf1 = *(const s16x8*)(qp + 32);
  }
  float mr[4], lrp[4];
  f32x4 o[4] = {};
#pragma unroll
  for (int r = 0; r < 4; ++r) { mr[r] = -1e30f; lrp[r] = 0.f; }
  ushort* Pw = &sP[w][0];

  auto stage = [&](int kb, int buf) {
    int row = t >> 3, cc = t & 7;
    int scz = cc ^ (row & 7);        // pre-swizzled source -> linear LDS dest
    gload_lds16(Kb + (size_t)(kb * 64 + row) * DKH + scz * 8, &sK[buf][w * 512]);
    gload_lds16(Vb + (size_t)row * SQL + kb * 64 + scz * 8, &sV[buf][w * 512]);
  };

  const int nkb = qhi + 1;
  stage(0, 0);
  for (int kb = 0; kb < nkb; ++kb) {
    const int cur = kb & 1;
    if (kb + 1 < nkb) {
      stage(kb + 1, cur ^ 1);                        // 2 vmem in flight
      asm volatile("s_waitcnt vmcnt(2)" ::: "memory");
    } else {
      asm volatile("s_waitcnt vmcnt(0)" ::: "memory");
    }
    __builtin_amdgcn_s_barrier();
    __builtin_amdgcn_sched_barrier(0);
    const bool act = setid || (kb <= qlo);
    if (act) {
      const ushort* pK = &sK[cur][0];
      const ushort* pV = &sV[cur][0];
      // QK^T
      f32x4 sc4[4];
      __builtin_amdgcn_s_setprio(1);
#pragma unroll
      for (int ktt = 0; ktt < 4; ++ktt) {
        int row = ktt * 16 + lcol;
        int c0 = lhi ^ (row & 7);
        int c1 = (lhi + 4) ^ (row & 7);
        s16x8 k0 = *(const s16x8*)(pK + row * 64 + c0 * 8);
        s16x8 k1 = *(const s16x8*)(pK + row * 64 + c1 * 8);
        f32x4 a = {};
        a = __builtin_amdgcn_mfma_f32_16x16x32_bf16(qf0, k0, a, 0, 0, 0);
        a = __builtin_amdgcn_mfma_f32_16x16x32_bf16(qf1, k1, a, 0, 0, 0);
        sc4[ktt] = a;
      }
      __builtin_amdgcn_s_setprio(0);
      // causal mask on the diagonal tile
      if (kb == qtile) {
#pragma unroll
        for (int ktt = 0; ktt < 4; ++ktt) {
          int kloc = ktt * 16 + lcol;
#pragma unroll
          for (int r = 0; r < 4; ++r)
            if (kloc > (w & 3) * 16 + lhi * 4 + r) sc4[ktt][r] = -1e30f;
        }
      }
      // online softmax (log2 domain), defer-max rescale
      float tm4[4];
#pragma unroll
      for (int r = 0; r < 4; ++r) {
        float tm = fmaxf(fmaxf(sc4[0][r], sc4[1][r]), fmaxf(sc4[2][r], sc4[3][r]));
        tm4[r] = rowmax16(tm);
      }
      bool grow = (tm4[0] > mr[0] + 8.f) || (tm4[1] > mr[1] + 8.f) ||
                  (tm4[2] > mr[2] + 8.f) || (tm4[3] > mr[3] + 8.f);
      if (__any((int)grow)) {
#pragma unroll
        for (int r = 0; r < 4; ++r) {
          float mn = fmaxf(mr[r], tm4[r]);
          float al = EXP2(mr[r] - mn);
          lrp[r] *= al;
          o[0][r] *= al; o[1][r] *= al; o[2][r] *= al; o[3][r] *= al;
          mr[r] = mn;
        }
      }
#pragma unroll
      for (int r = 0; r < 4; ++r) {
        float p0 = EXP2(sc4[0][r] - mr[r]);
        float p1 = EXP2(sc4[1][r] - mr[r]);
        float p2 = EXP2(sc4[2][r] - mr[r]);
        float p3 = EXP2(sc4[3][r] - mr[r]);
        lrp[r] += (p0 + p1) + (p2 + p3);
        uint2 pk;
        pk.x = cvtpk_bf16(p0, p1);
        pk.y = cvtpk_bf16(p2, p3);
        // permuted store: (k=ktt*16+lcol) -> idx 4*lcol+ktt; one b64 covers ktt 0..3
        *(uint2*)(Pw + (lhi * 4 + r) * 72 + lcol * 4) = pk;
      }
      // PV (Vt global pre-permuted to match the P permutation)
      __builtin_amdgcn_s_setprio(1);
#pragma unroll
      for (int kc = 0; kc < 2; ++kc) {
        s16x8 pf = *(const s16x8*)(Pw + lcol * 72 + kc * 32 + lhi * 8);
#pragma unroll
        for (int dt = 0; dt < 4; ++dt) {
          int row = dt * 16 + lcol;
          int cc = (lhi + 4 * kc) ^ (row & 7);
          s16x8 vf = *(const s16x8*)(pV + row * 64 + cc * 8);
          o[dt] = __builtin_amdgcn_mfma_f32_16x16x32_bf16(pf, vf, o[dt], 0, 0, 0);
        }
      }
      __builtin_amdgcn_s_setprio(0);
    }
    asm volatile("s_waitcnt lgkmcnt(0)" ::: "memory");
    __builtin_amdgcn_s_barrier();
  }

  // epilogue: reduce denominators over the 16 k-lanes, normalize, write Z
  const int b = bh >> 4, h = bh & 15;
#pragma unroll
  for (int r = 0; r < 4; ++r) {
    float sum = lrp[r];
    sum += __shfl_xor(sum, 1);
    sum += __shfl_xor(sum, 2);
    sum += __shfl_xor(sum, 4);
    sum += __shfl_xor(sum, 8);
    float inv = 1.0f / sum;
    int q = qr0 + lhi * 4 + r;
    size_t base = ((size_t)(b * SQL + q)) * DMODEL + h * DKH + lcol;
#pragma unroll
    for (int dt = 0; dt < 4; ++dt)
      Z[base + dt * 16] = f2bf(o[dt][r] * inv);
  }
}

// ---------------- launch ----------------
extern "C" void kernel_launch(void* const* d_in, const int* in_sizes, int n_in,
                              void* d_out, int out_size, void* d_ws, size_t ws_size,
                              hipStream_t stream) {
  const float* q = (const float*)d_in[0];
  const float* k = (const float*)d_in[1];
  const float* v = (const float*)d_in[2];
  // d_in[3] = causal mask (bool) -- derived analytically, ignored
  const float* wq = (const float*)d_in[4];
  const float* wk = (const float*)d_in[5];
  const float* wv = (const float*)d_in[6];
  const float* wo = (const float*)d_in[7];

  const size_t NBIG = (size_t)BSZ * SQL * DMODEL;   // 4194304
  const size_t NW = (size_t)DMODEL * DMODEL;        // 1048576
  ushort* qb = (ushort*)d_ws;
  ushort* kb = qb + NBIG;
  ushort* vb = kb + NBIG;
  ushort* wqb = vb + NBIG;
  ushort* wkb = wqb + NW;
  ushort* wvb = wkb + NW;
  ushort* wob = wvb + NW;
  ushort* Qh = wob + NW;
  ushort* Kh = Qh + NBIG;
  ushort* Vt = Kh + NBIG;
  ushort* Z  = Vt + NBIG;   // total 64 MiB of d_ws

  cvt_all<<<dim3(16384), 256, 0, stream>>>(q, k, v, wq, wk, wv, wo,
                                           qb, kb, vb, wqb, wkb, wvb, wob);
  gemm_qkv<<<dim3(32, 8, 3), 256, 0, stream>>>(qb, kb, vb, wqb, wkb, wvb, Qh, Kh, Vt);
  attn_fwd<<<dim3(16, BSZ * NHEAD), 512, 0, stream>>>(Qh, Kh, Vt, Z);
  gemm_out64<<<dim3(64, 8), 256, 0, stream>>>(Z, wob, (float*)d_out);
}

// Round 12
// 120.354 us; speedup vs baseline: 1.3402x; 1.0783x over previous
//
#include <hip/hip_runtime.h>
#include <hip/hip_bf16.h>
#include <stdint.h>

typedef short s16x8 __attribute__((ext_vector_type(8)));
typedef float f32x4 __attribute__((ext_vector_type(4)));

#define BSZ 2
#define SQL 2048
#define DMODEL 1024
#define NHEAD 16
#define DKH 64

#if __has_builtin(__builtin_amdgcn_exp2f)
#define EXP2(x) __builtin_amdgcn_exp2f(x)
#else
#define EXP2(x) exp2f(x)
#endif

// fp32 -> bf16 round-to-nearest-even
__device__ __forceinline__ ushort f2bf(float f) {
  uint32_t u = __float_as_uint(f);
  u += 0x7fffu + ((u >> 16) & 1u);
  return (ushort)(u >> 16);
}

// pack two f32 -> 2x bf16 in one u32 (lo -> low half), RNE
__device__ __forceinline__ uint32_t cvtpk_bf16(float lo, float hi) {
  uint32_t r;
  asm("v_cvt_pk_bf16_f32 %0, %1, %2" : "=v"(r) : "v"(lo), "v"(hi));
  return r;
}

// max-reduce across the 16-lane DPP row via row_ror 1,2,4,8 (VALU, no DS pipe)
__device__ __forceinline__ float rowmax16(float x) {
  x = fmaxf(x, __int_as_float(__builtin_amdgcn_update_dpp(0, __float_as_int(x), 0x121, 0xf, 0xf, true)));
  x = fmaxf(x, __int_as_float(__builtin_amdgcn_update_dpp(0, __float_as_int(x), 0x122, 0xf, 0xf, true)));
  x = fmaxf(x, __int_as_float(__builtin_amdgcn_update_dpp(0, __float_as_int(x), 0x124, 0xf, 0xf, true)));
  x = fmaxf(x, __int_as_float(__builtin_amdgcn_update_dpp(0, __float_as_int(x), 0x128, 0xf, 0xf, true)));
  return x;
}

// async global->LDS, 16B per lane. LDS dest must be wave-uniform base; HW adds lane*16.
__device__ __forceinline__ void gload_lds16(const ushort* g, ushort* l) {
  __builtin_amdgcn_global_load_lds((const __attribute__((address_space(1))) void*)g,
                                   (__attribute__((address_space(3))) void*)l,
                                   16, 0, 0);
}

// ---------------- fp32 -> bf16 conversion for the 4 weight matrices ----------------
__global__ void cvt_w(const float* __restrict__ wq, const float* __restrict__ wk,
                      const float* __restrict__ wv, const float* __restrict__ wo,
                      ushort* __restrict__ dwq, ushort* __restrict__ dwk,
                      ushort* __restrict__ dwv, ushort* __restrict__ dwo) {
  const float* s = (blockIdx.y == 0) ? wq : (blockIdx.y == 1) ? wk : (blockIdx.y == 2) ? wv : wo;
  ushort* d = (blockIdx.y == 0) ? dwq : (blockIdx.y == 1) ? dwk : (blockIdx.y == 2) ? dwv : dwo;
  int i = (blockIdx.x * 256 + threadIdx.x) * 4;
  float4 x = *(const float4*)(s + i);
  ushort4 o;
  o.x = f2bf(x.x); o.y = f2bf(x.y); o.z = f2bf(x.z); o.w = f2bf(x.w);
  *(ushort4*)(d + i) = o;
}

// epilogue for bf16 head-major / permuted-transposed-V outputs (r4-verified)
__device__ __forceinline__ void epi_heads(f32x4 (&acc)[4][4], ushort* D, float scale, bool vtrans) {
  const int lane = threadIdx.x & 63, w = threadIdx.x >> 6;
  const int m0 = blockIdx.x * 128, n0 = blockIdx.y * 128;
  const int wm = (w >> 1) * 64, wn = (w & 1) * 64;
#pragma unroll
  for (int mi = 0; mi < 4; ++mi)
#pragma unroll
    for (int ni = 0; ni < 4; ++ni)
#pragma unroll
      for (int r = 0; r < 4; ++r) {
        int m = m0 + wm + mi * 16 + (lane >> 4) * 4 + r;
        int n = n0 + wn + ni * 16 + (lane & 15);
        ushort bv = f2bf(acc[mi][ni][r] * scale);
        int b = m >> 11, s = m & 2047, h = n >> 6, d = n & 63;
        if (vtrans) {
          // k-permutation inside each 64-tile: idx(k) = (k&15)*4 + (k>>4)
          int sp = (s & ~63) | (((s & 15) << 2) | ((s >> 4) & 3));
          D[((size_t)((b * 16 + h) * 64 + d)) * 2048 + sp] = bv;   // V^T permuted
        } else {
          D[((size_t)((b * 16 + h) * 2048 + s)) * 64 + d] = bv;    // Qh/Kh [bh][s][d]
        }
      }
}

// ---------------- QKV projection GEMM, fp32-A staged directly via gload_lds16 ----------
// C[M,N] = A_f32[M,K] * B_bf16[N,K]^T. 128x128 tile, BK=32, 4 waves.
// A staged as raw fp32 (32KB/buf) with within-row chunk swizzle fc^=(row&7)
// (coalescing preserved; f32 fragment reads 2-way bank = free). Converted to
// bf16 at fragment-read via v_cvt_pk_bf16_f32 (RNE — identical to cvt pass).
// B (bf16 weights) staged as before with cs^=(row>>1)&3 swizzle.
__global__ __launch_bounds__(256) void gemm_qkv(const float* __restrict__ qf,
                                                const float* __restrict__ kf,
                                                const float* __restrict__ vf,
                                                const ushort* __restrict__ wqb,
                                                const ushort* __restrict__ wkb,
                                                const ushort* __restrict__ wvb,
                                                ushort* __restrict__ Qh,
                                                ushort* __restrict__ Kh,
                                                ushort* __restrict__ Vt) {
  __shared__ __align__(16) float sA32[2 * 4096];   // 2 x 128 rows x 32 f32 = 32KB
  __shared__ __align__(16) ushort sB[2 * 4096];    // 16KB
  const int z = blockIdx.z;
  const float* A = (z == 0) ? qf : (z == 1) ? kf : vf;
  const ushort* B = (z == 0) ? wqb : (z == 1) ? wkb : wvb;
  const int t = threadIdx.x, w = t >> 6, lane = t & 63;
  const int lrow = lane & 15, g = lane >> 4;
  const int swzB = (lrow >> 1) & 3;
  const int m0 = blockIdx.x * 128, n0 = blockIdx.y * 128;
  const int wm = (w >> 1) * 64, wn = (w & 1) * 64;
  f32x4 acc[4][4] = {};

  auto stage = [&](int kt, int buf) {
    // A: 1024 chunks of 16B (4 f32); LDS pos ci holds source fchunk (ci&7)^(row&7)
#pragma unroll
    for (int i2 = 0; i2 < 4; ++i2) {
      int ci = i2 * 256 + t;
      int row = ci >> 3;
      int fc = (ci & 7) ^ (row & 7);
      gload_lds16((const ushort*)(A + (size_t)(m0 + row) * 1024 + kt * 32 + fc * 4),
                  (ushort*)(sA32 + buf * 4096 + (i2 * 256 + w * 64) * 4));
    }
    // B: 512 chunks of 16B (8 bf16); within-row swizzle
#pragma unroll
    for (int i2 = 0; i2 < 2; ++i2) {
      int ci = i2 * 256 + t;
      int row = ci >> 2;
      int cs = (ci & 3) ^ ((row >> 1) & 3);
      gload_lds16(B + (size_t)(n0 + row) * 1024 + kt * 32 + cs * 8,
                  sB + buf * 4096 + (i2 * 256 + w * 64) * 8);
    }
  };

  stage(0, 0);
  for (int kt = 0; kt < 32; ++kt) {
    const int cur = kt & 1;
    if (kt < 31) {
      stage(kt + 1, cur ^ 1);                           // 6 vmem in flight
      asm volatile("s_waitcnt vmcnt(6)" ::: "memory");  // drain current tile
    } else {
      asm volatile("s_waitcnt vmcnt(0)" ::: "memory");
    }
    __builtin_amdgcn_s_barrier();
    __builtin_amdgcn_sched_barrier(0);
    const float* pA = sA32 + cur * 4096;
    const ushort* pB = sB + cur * 4096;
    const int gs = (g ^ swzB) * 8;
    s16x8 af[4], bfr[4];
#pragma unroll
    for (int mi = 0; mi < 4; ++mi) {
      int row = wm + mi * 16 + lrow;
      int f0 = (2 * g) ^ (row & 7);
      int f1 = (2 * g + 1) ^ (row & 7);
      f32x4 x0 = *(const f32x4*)(pA + row * 32 + f0 * 4);
      f32x4 x1 = *(const f32x4*)(pA + row * 32 + f1 * 4);
      union { uint32_t u[4]; s16x8 v; } cc;
      cc.u[0] = cvtpk_bf16(x0[0], x0[1]);
      cc.u[1] = cvtpk_bf16(x0[2], x0[3]);
      cc.u[2] = cvtpk_bf16(x1[0], x1[1]);
      cc.u[3] = cvtpk_bf16(x1[2], x1[3]);
      af[mi] = cc.v;
    }
#pragma unroll
    for (int ni = 0; ni < 4; ++ni)
      bfr[ni] = *(const s16x8*)(pB + (wn + ni * 16 + lrow) * 32 + gs);
    __builtin_amdgcn_s_setprio(1);
#pragma unroll
    for (int mi = 0; mi < 4; ++mi)
#pragma unroll
      for (int ni = 0; ni < 4; ++ni)
        acc[mi][ni] = __builtin_amdgcn_mfma_f32_16x16x32_bf16(af[mi], bfr[ni], acc[mi][ni], 0, 0, 0);
    __builtin_amdgcn_s_setprio(0);
    asm volatile("s_waitcnt lgkmcnt(0)" ::: "memory");
    __builtin_amdgcn_s_barrier();
  }

  ushort* D = (z == 0) ? Qh : (z == 1) ? Kh : Vt;
  // Q pre-scaled by 1/sqrt(dk) * log2(e) so softmax runs in exp2 domain
  epi_heads(acc, D, (z == 0) ? 0.18033688f : 1.0f, z == 2);
}

// ---------------- gemm_out: 64x128 tiles, within-row swizzle, Z x Wo^T -> fp32 -------
__global__ __launch_bounds__(256) void gemm_out64(const ushort* __restrict__ A,
                                                  const ushort* __restrict__ B,
                                                  float* __restrict__ D) {
  __shared__ __align__(16) ushort sA[2 * 2048];
  __shared__ __align__(16) ushort sB[2 * 4096];
  const int t = threadIdx.x, w = t >> 6, lane = t & 63;
  const int lrow = lane & 15, g = lane >> 4;
  const int swz = (lrow >> 1) & 3;
  const int m0 = blockIdx.x * 64, n0 = blockIdx.y * 128;
  const int wm = (w >> 1) * 32, wn = (w & 1) * 64;
  f32x4 acc[2][4] = {};

  auto stage = [&](int kt, int buf) {
    {
      int row = t >> 2;
      int cs = (t & 3) ^ ((row >> 1) & 3);
      gload_lds16(A + (size_t)(m0 + row) * 1024 + kt * 32 + cs * 8,
                  sA + buf * 2048 + (w * 64) * 8);
    }
#pragma unroll
    for (int i2 = 0; i2 < 2; ++i2) {
      int ci = i2 * 256 + t;
      int row = ci >> 2;
      int cs = (ci & 3) ^ ((row >> 1) & 3);
      gload_lds16(B + (size_t)(n0 + row) * 1024 + kt * 32 + cs * 8,
                  sB + buf * 4096 + (i2 * 256 + w * 64) * 8);
    }
  };

  stage(0, 0);
  for (int kt = 0; kt < 32; ++kt) {
    const int cur = kt & 1;
    if (kt < 31) {
      stage(kt + 1, cur ^ 1);
      asm volatile("s_waitcnt vmcnt(3)" ::: "memory");
    } else {
      asm volatile("s_waitcnt vmcnt(0)" ::: "memory");
    }
    __builtin_amdgcn_s_barrier();
    __builtin_amdgcn_sched_barrier(0);
    const ushort* pA = sA + cur * 2048;
    const ushort* pB = sB + cur * 4096;
    const int gs = (g ^ swz) * 8;
    s16x8 af[2], bfr[4];
#pragma unroll
    for (int mi = 0; mi < 2; ++mi)
      af[mi] = *(const s16x8*)(pA + (wm + mi * 16 + lrow) * 32 + gs);
#pragma unroll
    for (int ni = 0; ni < 4; ++ni)
      bfr[ni] = *(const s16x8*)(pB + (wn + ni * 16 + lrow) * 32 + gs);
    __builtin_amdgcn_s_setprio(1);
#pragma unroll
    for (int mi = 0; mi < 2; ++mi)
#pragma unroll
      for (int ni = 0; ni < 4; ++ni)
        acc[mi][ni] = __builtin_amdgcn_mfma_f32_16x16x32_bf16(af[mi], bfr[ni], acc[mi][ni], 0, 0, 0);
    __builtin_amdgcn_s_setprio(0);
    asm volatile("s_waitcnt lgkmcnt(0)" ::: "memory");
    __builtin_amdgcn_s_barrier();
  }

#pragma unroll
  for (int mi = 0; mi < 2; ++mi)
#pragma unroll
    for (int ni = 0; ni < 4; ++ni)
#pragma unroll
      for (int r = 0; r < 4; ++r) {
        int m = m0 + wm + mi * 16 + (lane >> 4) * 4 + r;
        int n = n0 + wn + ni * 16 + (lane & 15);
        D[(size_t)m * 1024 + n] = acc[mi][ni][r];
      }
}

// ---------------- causal flash attention (r11 kernel + XCD-locality relabel) ----------
// grid (16, 32) = 512 blocks. lid -> (p, bh) relabeled so the 16 p-blocks of one
// bh land on one XCD (4 bh per XCD L2 = 2MB K/V resident). 512 threads; waves 0-3
// own q-tile p, waves 4-7 own 31-p. KV tiles of 64, dbuf, counted vmcnt(2).
// P stored k-permuted via b64; Vt global pre-permuted to match.
__global__ __launch_bounds__(512) void attn_fwd(const ushort* __restrict__ Qh,
                                                const ushort* __restrict__ Kh,
                                                const ushort* __restrict__ Vt,
                                                ushort* __restrict__ Z) {
  __shared__ __align__(16) ushort sK[2][64 * 64];   // [k][d], chunk-XOR swizzled
  __shared__ __align__(16) ushort sV[2][64 * 64];   // [d][pos], chunk-XOR swizzled
  __shared__ __align__(16) ushort sP[8][16 * 72];   // per-wave P (k-permuted cols)
  const int t = threadIdx.x, w = t >> 6, lane = t & 63;
  const int lcol = lane & 15, lhi = lane >> 4;
  const int lid = blockIdx.x + 16 * blockIdx.y;     // 0..511
  const int p = lid >> 5;                           // 0..15
  const int bh = (lid & 7) * 4 + ((lid >> 3) & 3);  // bijective 0..31; same-bh -> same XCD
  const int qlo = p, qhi = 31 - p;
  const int setid = w >> 2;
  const int qtile = setid ? qhi : qlo;
  const int qr0 = qtile * 64 + (w & 3) * 16;
  const ushort* Qb = Qh + (size_t)bh * SQL * DKH;
  const ushort* Kb = Kh + (size_t)bh * SQL * DKH;
  const ushort* Vb = Vt + (size_t)bh * DKH * SQL;

  s16x8 qf0, qf1;
  {
    const ushort* qp = Qb + (size_t)(qr0 + lcol) * DKH + lhi * 8;
    qf0 = *(const s16x8*)qp;
    qf1 = *(const s16x8*)(qp + 32);
  }
  float mr[4], lrp[4];
  f32x4 o[4] = {};
#pragma unroll
  for (int r = 0; r < 4; ++r) { mr[r] = -1e30f; lrp[r] = 0.f; }
  ushort* Pw = &sP[w][0];

  auto stage = [&](int kb, int buf) {
    int row = t >> 3, cc = t & 7;
    int scz = cc ^ (row & 7);        // pre-swizzled source -> linear LDS dest
    gload_lds16(Kb + (size_t)(kb * 64 + row) * DKH + scz * 8, &sK[buf][w * 512]);
    gload_lds16(Vb + (size_t)row * SQL + kb * 64 + scz * 8, &sV[buf][w * 512]);
  };

  const int nkb = qhi + 1;
  stage(0, 0);
  for (int kb = 0; kb < nkb; ++kb) {
    const int cur = kb & 1;
    if (kb + 1 < nkb) {
      stage(kb + 1, cur ^ 1);                        // 2 vmem in flight
      asm volatile("s_waitcnt vmcnt(2)" ::: "memory");
    } else {
      asm volatile("s_waitcnt vmcnt(0)" ::: "memory");
    }
    __builtin_amdgcn_s_barrier();
    __builtin_amdgcn_sched_barrier(0);
    const bool act = setid || (kb <= qlo);
    if (act) {
      const ushort* pK = &sK[cur][0];
      const ushort* pV = &sV[cur][0];
      // QK^T
      f32x4 sc4[4];
      __builtin_amdgcn_s_setprio(1);
#pragma unroll
      for (int ktt = 0; ktt < 4; ++ktt) {
        int row = ktt * 16 + lcol;
        int c0 = lhi ^ (row & 7);
        int c1 = (lhi + 4) ^ (row & 7);
        s16x8 k0 = *(const s16x8*)(pK + row * 64 + c0 * 8);
        s16x8 k1 = *(const s16x8*)(pK + row * 64 + c1 * 8);
        f32x4 a = {};
        a = __builtin_amdgcn_mfma_f32_16x16x32_bf16(qf0, k0, a, 0, 0, 0);
        a = __builtin_amdgcn_mfma_f32_16x16x32_bf16(qf1, k1, a, 0, 0, 0);
        sc4[ktt] = a;
      }
      __builtin_amdgcn_s_setprio(0);
      // causal mask on the diagonal tile
      if (kb == qtile) {
#pragma unroll
        for (int ktt = 0; ktt < 4; ++ktt) {
          int kloc = ktt * 16 + lcol;
#pragma unroll
          for (int r = 0; r < 4; ++r)
            if (kloc > (w & 3) * 16 + lhi * 4 + r) sc4[ktt][r] = -1e30f;
        }
      }
      // online softmax (log2 domain), defer-max rescale
      float tm4[4];
#pragma unroll
      for (int r = 0; r < 4; ++r) {
        float tm = fmaxf(fmaxf(sc4[0][r], sc4[1][r]), fmaxf(sc4[2][r], sc4[3][r]));
        tm4[r] = rowmax16(tm);
      }
      bool grow = (tm4[0] > mr[0] + 8.f) || (tm4[1] > mr[1] + 8.f) ||
                  (tm4[2] > mr[2] + 8.f) || (tm4[3] > mr[3] + 8.f);
      if (__any((int)grow)) {
#pragma unroll
        for (int r = 0; r < 4; ++r) {
          float mn = fmaxf(mr[r], tm4[r]);
          float al = EXP2(mr[r] - mn);
          lrp[r] *= al;
          o[0][r] *= al; o[1][r] *= al; o[2][r] *= al; o[3][r] *= al;
          mr[r] = mn;
        }
      }
#pragma unroll
      for (int r = 0; r < 4; ++r) {
        float p0 = EXP2(sc4[0][r] - mr[r]);
        float p1 = EXP2(sc4[1][r] - mr[r]);
        float p2 = EXP2(sc4[2][r] - mr[r]);
        float p3 = EXP2(sc4[3][r] - mr[r]);
        lrp[r] += (p0 + p1) + (p2 + p3);
        uint2 pk;
        pk.x = cvtpk_bf16(p0, p1);
        pk.y = cvtpk_bf16(p2, p3);
        // permuted store: (k=ktt*16+lcol) -> idx 4*lcol+ktt; one b64 covers ktt 0..3
        *(uint2*)(Pw + (lhi * 4 + r) * 72 + lcol * 4) = pk;
      }
      // PV (Vt global pre-permuted to match the P permutation)
      __builtin_amdgcn_s_setprio(1);
#pragma unroll
      for (int kc = 0; kc < 2; ++kc) {
        s16x8 pf = *(const s16x8*)(Pw + lcol * 72 + kc * 32 + lhi * 8);
#pragma unroll
        for (int dt = 0; dt < 4; ++dt) {
          int row = dt * 16 + lcol;
          int cc = (lhi + 4 * kc) ^ (row & 7);
          s16x8 vf = *(const s16x8*)(pV + row * 64 + cc * 8);
          o[dt] = __builtin_amdgcn_mfma_f32_16x16x32_bf16(pf, vf, o[dt], 0, 0, 0);
        }
      }
      __builtin_amdgcn_s_setprio(0);
    }
    asm volatile("s_waitcnt lgkmcnt(0)" ::: "memory");
    __builtin_amdgcn_s_barrier();
  }

  // epilogue: reduce denominators over the 16 k-lanes, normalize, write Z
  const int b = bh >> 4, h = bh & 15;
#pragma unroll
  for (int r = 0; r < 4; ++r) {
    float sum = lrp[r];
    sum += __shfl_xor(sum, 1);
    sum += __shfl_xor(sum, 2);
    sum += __shfl_xor(sum, 4);
    sum += __shfl_xor(sum, 8);
    float inv = 1.0f / sum;
    int q = qr0 + lhi * 4 + r;
    size_t base = ((size_t)(b * SQL + q)) * DMODEL + h * DKH + lcol;
#pragma unroll
    for (int dt = 0; dt < 4; ++dt)
      Z[base + dt * 16] = f2bf(o[dt][r] * inv);
  }
}

// ---------------- launch ----------------
extern "C" void kernel_launch(void* const* d_in, const int* in_sizes, int n_in,
                              void* d_out, int out_size, void* d_ws, size_t ws_size,
                              hipStream_t stream) {
  const float* q = (const float*)d_in[0];
  const float* k = (const float*)d_in[1];
  const float* v = (const float*)d_in[2];
  // d_in[3] = causal mask (bool) -- derived analytically, ignored
  const float* wq = (const float*)d_in[4];
  const float* wk = (const float*)d_in[5];
  const float* wv = (const float*)d_in[6];
  const float* wo = (const float*)d_in[7];

  const size_t NBIG = (size_t)BSZ * SQL * DMODEL;   // 4194304
  const size_t NW = (size_t)DMODEL * DMODEL;        // 1048576
  ushort* wqb = (ushort*)d_ws;
  ushort* wkb = wqb + NW;
  ushort* wvb = wkb + NW;
  ushort* wob = wvb + NW;
  ushort* Qh = wob + NW;
  ushort* Kh = Qh + NBIG;
  ushort* Vt = Kh + NBIG;
  ushort* Z  = Vt + NBIG;   // total 40 MiB of d_ws

  cvt_w<<<dim3(1024, 4), 256, 0, stream>>>(wq, wk, wv, wo, wqb, wkb, wvb, wob);
  gemm_qkv<<<dim3(32, 8, 3), 256, 0, stream>>>(q, k, v, wqb, wkb, wvb, Qh, Kh, Vt);
  attn_fwd<<<dim3(16, BSZ * NHEAD), 512, 0, stream>>>(Qh, Kh, Vt, Z);
  gemm_out64<<<dim3(64, 8), 256, 0, stream>>>(Z, wob, (float*)d_out);
}